// Round 2
// baseline (1330.303 us; speedup 1.0000x reference)
//
#include <hip/hip_runtime.h>

typedef short s16x8 __attribute__((ext_vector_type(8)));   // 8 bf16 MFMA frag (per guide §3)
typedef float f32x4 __attribute__((ext_vector_type(4)));
typedef unsigned short u16;
typedef u16 u16x8 __attribute__((ext_vector_type(8)));

constexpr int TN = 16384;
constexpr int DN = 1024;
constexpr int EN = 8;
constexpr int HN = 4096;
constexpr int CAPN = 2048;  // CAP_FACTOR * T / E

__device__ __forceinline__ u16 f2bf(float x){  // round-to-nearest-even f32 -> bf16
  unsigned u = __float_as_uint(x);
  u = (u + 0x7fffu + ((u >> 16) & 1u)) >> 16;
  return (u16)u;
}

// ---------- fp32 (E,R,C) -> bf16 (E,C,R)  (weights pre-transpose+convert) ----------
__global__ __launch_bounds__(256) void k_transpose(const float* __restrict__ in, u16* __restrict__ out,
                                                   int R, int C){
  __shared__ float tile[64][65];  // +1 pad: column reads conflict-free
  const int e = blockIdx.z;
  const int r0 = blockIdx.y * 64, c0 = blockIdx.x * 64;
  const float* ine = in + (size_t)e * R * C;
  u16* oute = out + (size_t)e * R * C;
  const int t = threadIdx.x;
  {
    const int dr = t >> 2, cs = (t & 3) * 16;
    const float* src = ine + (size_t)(r0 + dr) * C + (c0 + cs);
    #pragma unroll
    for (int i = 0; i < 4; ++i){
      f32x4 v = *reinterpret_cast<const f32x4*>(src + i * 4);
      #pragma unroll
      for (int c = 0; c < 4; ++c) tile[dr][cs + i*4 + c] = v[c];
    }
  }
  __syncthreads();
  {
    const int dn = t >> 2, ks = (t & 3) * 16;
    u16x8 lo, hi;
    #pragma unroll
    for (int i = 0; i < 8; ++i) lo[i] = f2bf(tile[ks + i][dn]);
    #pragma unroll
    for (int i = 0; i < 8; ++i) hi[i] = f2bf(tile[ks + 8 + i][dn]);
    u16* dst = oute + (size_t)(c0 + dn) * R + (r0 + ks);
    *reinterpret_cast<u16x8*>(dst) = lo;
    *reinterpret_cast<u16x8*>(dst + 8) = hi;
  }
}

// ---------- router GEMM1: r1 = relu(x @ wr1 + br1), fp32 SGEMM 128x128x32 ----------
__global__ __launch_bounds__(256) void k_router_gemm1(const float* __restrict__ X, const float* __restrict__ W,
                                                      const float* __restrict__ bias, float* __restrict__ Y){
  __shared__ float As[32][128];  // [k][m] (A transposed in LDS)
  __shared__ float Bs[32][128];  // [k][n]
  const int m0 = blockIdx.y * 128, n0 = blockIdx.x * 128;
  const int t = threadIdx.x;
  const int tx = t & 15, ty = t >> 4;
  float acc[8][8] = {};
  const int am = t >> 1, aseg = (t & 1) * 16;
  for (int k0 = 0; k0 < DN; k0 += 32){
    f32x4 av[4], bv[4];
    #pragma unroll
    for (int i = 0; i < 4; ++i)
      av[i] = *reinterpret_cast<const f32x4*>(X + (size_t)(m0 + am) * DN + k0 + aseg + i*4);
    #pragma unroll
    for (int j = 0; j < 4; ++j){
      int flat = t + 256*j;
      int kb = flat >> 5, nb = (flat & 31) * 4;
      bv[j] = *reinterpret_cast<const f32x4*>(W + (size_t)(k0 + kb) * DN + n0 + nb);
    }
    __syncthreads();   // protect previous iteration's LDS reads
    #pragma unroll
    for (int i = 0; i < 4; ++i)
      #pragma unroll
      for (int c = 0; c < 4; ++c)
        As[aseg + i*4 + c][am] = av[i][c];
    #pragma unroll
    for (int j = 0; j < 4; ++j){
      int flat = t + 256*j;
      int kb = flat >> 5, nb = (flat & 31) * 4;
      *reinterpret_cast<f32x4*>(&Bs[kb][nb]) = bv[j];
    }
    __syncthreads();
    #pragma unroll
    for (int k = 0; k < 32; ++k){
      float a[8], b[8];
      *reinterpret_cast<f32x4*>(a)     = *reinterpret_cast<const f32x4*>(&As[k][ty*8]);
      *reinterpret_cast<f32x4*>(a + 4) = *reinterpret_cast<const f32x4*>(&As[k][ty*8 + 4]);
      *reinterpret_cast<f32x4*>(b)     = *reinterpret_cast<const f32x4*>(&Bs[k][tx*8]);
      *reinterpret_cast<f32x4*>(b + 4) = *reinterpret_cast<const f32x4*>(&Bs[k][tx*8 + 4]);
      #pragma unroll
      for (int i = 0; i < 8; ++i)
        #pragma unroll
        for (int jj = 0; jj < 8; ++jj)
          acc[i][jj] = fmaf(a[i], b[jj], acc[i][jj]);
    }
  }
  float bcol[8];
  #pragma unroll
  for (int j = 0; j < 8; ++j) bcol[j] = bias[n0 + tx*8 + j];
  #pragma unroll
  for (int i = 0; i < 8; ++i){
    float* dst = Y + (size_t)(m0 + ty*8 + i) * DN + n0 + tx*8;
    f32x4 v0, v1;
    #pragma unroll
    for (int j = 0; j < 4; ++j){ float v = acc[i][j] + bcol[j];     v0[j] = v > 0.f ? v : 0.f; }
    #pragma unroll
    for (int j = 0; j < 4; ++j){ float v = acc[i][4+j] + bcol[4+j]; v1[j] = v > 0.f ? v : 0.f; }
    *reinterpret_cast<f32x4*>(dst)     = v0;
    *reinterpret_cast<f32x4*>(dst + 4) = v1;
  }
}

// ---------- router logits + softmax + argmax: eid[t], gate[t] = max prob ----------
__global__ __launch_bounds__(256) void k_router_logits(const float* __restrict__ R1, const float* __restrict__ W2,
                                                       const float* __restrict__ B2, int* __restrict__ eid,
                                                       float* __restrict__ gate){
  __shared__ float w2s[EN][DN];  // transposed [e][k]: bank = k%32 -> 2-way max
  __shared__ float b2s[EN];
  const int t = threadIdx.x;
  #pragma unroll
  for (int j = 0; j < 32; ++j){
    int flat = t + 256*j;
    w2s[flat & 7][flat >> 3] = W2[flat];
  }
  if (t < EN) b2s[t] = B2[t];
  __syncthreads();
  const int wid = t >> 6, lane = t & 63;
  const int token = blockIdx.x * 4 + wid;
  const float* row = R1 + (size_t)token * DN;
  float acc[8] = {};
  for (int i = 0; i < 16; ++i){
    int k = lane + 64*i;             // fully-coalesced scalar loads
    float v = row[k];
    #pragma unroll
    for (int e = 0; e < 8; ++e) acc[e] = fmaf(v, w2s[e][k], acc[e]);
  }
  #pragma unroll
  for (int e = 0; e < 8; ++e){
    float s = acc[e];
    #pragma unroll
    for (int off = 32; off > 0; off >>= 1) s += __shfl_xor(s, off);
    acc[e] = s + b2s[e];
  }
  float best = acc[0]; int be = 0;
  #pragma unroll
  for (int e = 1; e < 8; ++e) if (acc[e] > best){ best = acc[e]; be = e; }  // first-max, matches argmax
  float sum = 0.f;
  #pragma unroll
  for (int e = 0; e < 8; ++e) sum += __expf(acc[e] - best);
  if (lane == 0){ eid[token] = be; gate[token] = 1.0f / sum; }  // gate = probs[t, eid]
}

// ---------- dispatch: per-chunk histogram -> exclusive scan -> slot assignment ----------
__global__ __launch_bounds__(256) void k_count(const int* __restrict__ eid, int* __restrict__ counts){
  __shared__ int h[EN];
  const int t = threadIdx.x;
  if (t < EN) h[t] = 0;
  __syncthreads();
  atomicAdd(&h[eid[blockIdx.x * 256 + t]], 1);
  __syncthreads();
  if (t < EN) counts[blockIdx.x * EN + t] = h[t];
}

__global__ void k_scan(const int* __restrict__ counts, int* __restrict__ offs){
  const int e = threadIdx.x;
  if (e < EN){
    int run = 0;
    for (int c = 0; c < TN/256; ++c){
      offs[c * EN + e] = run;
      run += counts[c * EN + e];
    }
  }
}

__global__ __launch_bounds__(256) void k_assign(const int* __restrict__ eid, const int* __restrict__ offs,
                                                int* __restrict__ idx){
  __shared__ int wcnt[4][EN];
  const int t = threadIdx.x;
  const int w = t >> 6, lane = t & 63;
  const int token = blockIdx.x * 256 + t;
  const int e = eid[token];
  unsigned long long mymask = 0;
  #pragma unroll
  for (int ee = 0; ee < EN; ++ee){
    unsigned long long m = __ballot(e == ee);
    if (ee == e) mymask = m;
    if (lane == 0) wcnt[w][ee] = __popcll(m);
  }
  const int rank = __popcll(mymask & ((1ull << lane) - 1ull));
  __syncthreads();
  int pre = 0;
  for (int wi = 0; wi < w; ++wi) pre += wcnt[wi][e];
  const int pos = offs[blockIdx.x * EN + e] + pre + rank;  // exact cumsum-order rank
  if (pos < CAPN) idx[e * CAPN + pos] = token;             // else dropped
}

// ---------- gather x rows -> bf16 xe[slot][k] (zeros for empty slots) ----------
__global__ __launch_bounds__(256) void k_gather(const float* __restrict__ X, const int* __restrict__ idx,
                                                u16* __restrict__ xe){
  const int slot = blockIdx.x;
  const int tok = idx[slot];
  const int t = threadIdx.x;
  unsigned lo = 0, hi = 0;
  if (tok >= 0){
    f32x4 v = *reinterpret_cast<const f32x4*>(X + (size_t)tok * DN + t*4);
    lo = (unsigned)f2bf(v[0]) | ((unsigned)f2bf(v[1]) << 16);
    hi = (unsigned)f2bf(v[2]) | ((unsigned)f2bf(v[3]) << 16);
  }
  uint2 o; o.x = lo; o.y = hi;
  *reinterpret_cast<uint2*>(xe + (size_t)slot * DN + t*4) = o;
}

// ---------- expert GEMMs, bf16 MFMA 16x16x32, 128x128x32 tiles, 4 waves 2x2 ----------
// A: bf16 [E*CAPN][K] row-major; Bt: bf16 [E][N][K] (pre-transposed weights)
// EPI 0: Hout = bf16 relu(A@B + b1)     EPI 1: Out[token] = (A@B + b2) * gate[token]
template<int EPI>
__global__ __launch_bounds__(256) void k_ffn(const u16* __restrict__ A, const u16* __restrict__ Bt,
                                             const float* __restrict__ bias, const int* __restrict__ idx,
                                             const float* __restrict__ gate, u16* __restrict__ Hout,
                                             float* __restrict__ Out, int K, int N){
  constexpr int LDSW = 40;                 // 32 + 8 pad: 80B row stride -> frag reads conflict-free
  __shared__ u16 As[128 * LDSW];
  __shared__ u16 Bs[128 * LDSW];
  const int e = blockIdx.z;
  const int m0 = blockIdx.y * 128, n0 = blockIdx.x * 128;
  const u16* Ae = A + ((size_t)e * CAPN + m0) * K;
  const u16* Be = Bt + ((size_t)e * N + n0) * K;
  const int t = threadIdx.x;
  const int wid = t >> 6, lane = t & 63;
  const int wr = wid >> 1, wc = wid & 1;
  const int r16 = lane & 15, kseg = lane >> 4;
  f32x4 acc[4][4] = {};
  const int srow = t >> 1, sseg = (t & 1) * 16;
  const u16* aptr = Ae + (size_t)srow * K + sseg;
  const u16* bptr = Be + (size_t)srow * K + sseg;
  for (int k0 = 0; k0 < K; k0 += 32){
    uint4 a0 = *reinterpret_cast<const uint4*>(aptr + k0);
    uint4 a1 = *reinterpret_cast<const uint4*>(aptr + k0 + 8);
    uint4 b0 = *reinterpret_cast<const uint4*>(bptr + k0);
    uint4 b1 = *reinterpret_cast<const uint4*>(bptr + k0 + 8);
    __syncthreads();
    *reinterpret_cast<uint4*>(&As[srow * LDSW + sseg])     = a0;
    *reinterpret_cast<uint4*>(&As[srow * LDSW + sseg + 8]) = a1;
    *reinterpret_cast<uint4*>(&Bs[srow * LDSW + sseg])     = b0;
    *reinterpret_cast<uint4*>(&Bs[srow * LDSW + sseg + 8]) = b1;
    __syncthreads();
    s16x8 af[4], bf[4];
    #pragma unroll
    for (int fr = 0; fr < 4; ++fr)
      af[fr] = *reinterpret_cast<const s16x8*>(&As[(wr*64 + fr*16 + r16) * LDSW + kseg*8]);
    #pragma unroll
    for (int fc = 0; fc < 4; ++fc)
      bf[fc] = *reinterpret_cast<const s16x8*>(&Bs[(wc*64 + fc*16 + r16) * LDSW + kseg*8]);
    #pragma unroll
    for (int fr = 0; fr < 4; ++fr)
      #pragma unroll
      for (int fc = 0; fc < 4; ++fc)
        acc[fr][fc] = __builtin_amdgcn_mfma_f32_16x16x32_bf16(af[fr], bf[fc], acc[fr][fc], 0, 0, 0);
  }
  // C/D layout: col = lane&15, row = (lane>>4)*4 + reg  [guide §3, m89-verified]
  if (EPI == 0){
    #pragma unroll
    for (int fc = 0; fc < 4; ++fc){
      const int col = n0 + wc*64 + fc*16 + r16;
      const float bc = bias[e * N + col];
      #pragma unroll
      for (int fr = 0; fr < 4; ++fr){
        #pragma unroll
        for (int r = 0; r < 4; ++r){
          const int row = m0 + wr*64 + fr*16 + kseg*4 + r;
          float v = acc[fr][fc][r] + bc;
          v = v > 0.f ? v : 0.f;
          Hout[((size_t)e * CAPN + row) * N + col] = f2bf(v);
        }
      }
    }
  } else {
    #pragma unroll
    for (int fr = 0; fr < 4; ++fr){
      #pragma unroll
      for (int r = 0; r < 4; ++r){
        const int row = m0 + wr*64 + fr*16 + kseg*4 + r;
        const int tok = idx[e * CAPN + row];
        if (tok < 0) continue;                    // empty slot
        const float g = gate[tok];
        #pragma unroll
        for (int fc = 0; fc < 4; ++fc){
          const int col = n0 + wc*64 + fc*16 + r16;
          Out[(size_t)tok * DN + col] = (acc[fr][fc][r] + bias[e * N + col]) * g;
        }
      }
    }
  }
}

extern "C" void kernel_launch(void* const* d_in, const int* in_sizes, int n_in,
                              void* d_out, int out_size, void* d_ws, size_t ws_size,
                              hipStream_t stream){
  const float* x   = (const float*)d_in[0];
  const float* wr1 = (const float*)d_in[1];
  const float* br1 = (const float*)d_in[2];
  const float* wr2 = (const float*)d_in[3];
  const float* br2 = (const float*)d_in[4];
  const float* w1  = (const float*)d_in[5];
  const float* b1  = (const float*)d_in[6];
  const float* w2  = (const float*)d_in[7];
  const float* b2  = (const float*)d_in[8];
  float* out = (float*)d_out;

  char* ws = (char*)d_ws;
  size_t off = 0;
  auto walloc = [&](size_t bytes) -> void* {
    void* p = ws + off;
    off += (bytes + 255) & ~(size_t)255;
    return p;
  };
  u16* hbuf   = (u16*)walloc((size_t)EN * CAPN * HN * 2);   // 128 MB; first 64 MB doubles as r1
  float* r1   = (float*)hbuf;                               // dead before ffn1 writes hbuf
  u16* xe     = (u16*)walloc((size_t)EN * CAPN * DN * 2);   // 32 MB
  u16* w1T    = (u16*)walloc((size_t)EN * HN * DN * 2);     // 64 MB
  u16* w2T    = (u16*)walloc((size_t)EN * HN * DN * 2);     // 64 MB
  int* eid    = (int*)walloc(TN * 4);
  float* gate = (float*)walloc(TN * 4);
  int* counts = (int*)walloc((TN/256) * EN * 4);
  int* offs   = (int*)walloc((TN/256) * EN * 4);
  int* idx    = (int*)walloc(EN * CAPN * 4);
  (void)in_sizes; (void)n_in; (void)out_size; (void)ws_size;

  k_transpose<<<dim3(HN/64, DN/64, EN), 256, 0, stream>>>(w1, w1T, DN, HN);  // (E,D,H)->(E,H,D)
  k_transpose<<<dim3(DN/64, HN/64, EN), 256, 0, stream>>>(w2, w2T, HN, DN);  // (E,H,D)->(E,D,H)
  k_router_gemm1<<<dim3(DN/128, TN/128), 256, 0, stream>>>(x, wr1, br1, r1);
  k_router_logits<<<dim3(TN/4), 256, 0, stream>>>(r1, wr2, br2, eid, gate);
  k_count<<<dim3(TN/256), 256, 0, stream>>>(eid, counts);
  k_scan<<<dim3(1), 64, 0, stream>>>(counts, offs);
  hipMemsetAsync(idx, 0xFF, (size_t)EN * CAPN * 4, stream);                  // -1 = empty slot
  k_assign<<<dim3(TN/256), 256, 0, stream>>>(eid, offs, idx);
  k_gather<<<dim3(EN * CAPN), 256, 0, stream>>>(x, idx, xe);
  k_ffn<0><<<dim3(HN/128, CAPN/128, EN), 256, 0, stream>>>(xe, w1T, b1, nullptr, nullptr, hbuf, nullptr, DN, HN);
  hipMemsetAsync(d_out, 0, (size_t)TN * DN * 4, stream);
  k_ffn<1><<<dim3(DN/128, CAPN/128, EN), 256, 0, stream>>>(hbuf, w2T, b2, idx, gate, nullptr, out, HN, DN);
}

// Round 3
// 1217.144 us; speedup vs baseline: 1.0930x; 1.0930x over previous
//
#include <hip/hip_runtime.h>

typedef short s16x8 __attribute__((ext_vector_type(8)));   // 8 bf16 MFMA frag (per guide §3)
typedef float f32x4 __attribute__((ext_vector_type(4)));
typedef unsigned short u16;
typedef u16 u16x8 __attribute__((ext_vector_type(8)));

constexpr int TN = 16384;
constexpr int DN = 1024;
constexpr int EN = 8;
constexpr int HN = 4096;
constexpr int CAPN = 2048;  // CAP_FACTOR * T / E

// async global->LDS, 16B per lane; lds ptr must be wave-uniform (lane*16 auto-added)
#define GLOAD16(g, l) __builtin_amdgcn_global_load_lds( \
    (const __attribute__((address_space(1))) unsigned int*)(g), \
    (__attribute__((address_space(3))) unsigned int*)(l), 16, 0, 0)

__device__ __forceinline__ u16 f2bf(float x){  // round-to-nearest-even f32 -> bf16
  unsigned u = __float_as_uint(x);
  u = (u + 0x7fffu + ((u >> 16) & 1u)) >> 16;
  return (u16)u;
}

// ---------- fp32 (E,R,C) -> bf16 (E,C,R)  (weights pre-transpose+convert) ----------
__global__ __launch_bounds__(256) void k_transpose(const float* __restrict__ in, u16* __restrict__ out,
                                                   int R, int C){
  __shared__ float tile[64][65];  // +1 pad: column reads conflict-free
  const int e = blockIdx.z;
  const int r0 = blockIdx.y * 64, c0 = blockIdx.x * 64;
  const float* ine = in + (size_t)e * R * C;
  u16* oute = out + (size_t)e * R * C;
  const int t = threadIdx.x;
  {
    const int dr = t >> 2, cs = (t & 3) * 16;
    const float* src = ine + (size_t)(r0 + dr) * C + (c0 + cs);
    #pragma unroll
    for (int i = 0; i < 4; ++i){
      f32x4 v = *reinterpret_cast<const f32x4*>(src + i * 4);
      #pragma unroll
      for (int c = 0; c < 4; ++c) tile[dr][cs + i*4 + c] = v[c];
    }
  }
  __syncthreads();
  {
    const int dn = t >> 2, ks = (t & 3) * 16;
    u16x8 lo, hi;
    #pragma unroll
    for (int i = 0; i < 8; ++i) lo[i] = f2bf(tile[ks + i][dn]);
    #pragma unroll
    for (int i = 0; i < 8; ++i) hi[i] = f2bf(tile[ks + 8 + i][dn]);
    u16* dst = oute + (size_t)(c0 + dn) * R + (r0 + ks);
    *reinterpret_cast<u16x8*>(dst) = lo;
    *reinterpret_cast<u16x8*>(dst + 8) = hi;
  }
}

// ---------- router GEMM1: r1 = relu(x @ wr1 + br1), fp32 SGEMM 128x128x32 ----------
// Fragment remap vs R0: each thread owns rows {ty*4..+3, 64+ty*4..+3} x cols {tx*4..+3, 64+tx*4..+3}.
// B-frag reads at 4*tx*4B stride-16B -> bank-start 4*tx mod 32 = 2-way (free, m136) vs old 4-way.
// Per-dot k-accumulation order unchanged -> r1 bitwise identical -> routing unchanged.
__global__ __launch_bounds__(256) void k_router_gemm1(const float* __restrict__ X, const float* __restrict__ W,
                                                      const float* __restrict__ bias, float* __restrict__ Y){
  __shared__ float As[32][128];  // [k][m] (A transposed in LDS)
  __shared__ float Bs[32][128];  // [k][n]
  const int m0 = blockIdx.y * 128, n0 = blockIdx.x * 128;
  const int t = threadIdx.x;
  const int tx = t & 15, ty = t >> 4;
  float acc[8][8] = {};
  const int am = t >> 1, aseg = (t & 1) * 16;
  for (int k0 = 0; k0 < DN; k0 += 32){
    f32x4 av[4], bv[4];
    #pragma unroll
    for (int i = 0; i < 4; ++i)
      av[i] = *reinterpret_cast<const f32x4*>(X + (size_t)(m0 + am) * DN + k0 + aseg + i*4);
    #pragma unroll
    for (int j = 0; j < 4; ++j){
      int flat = t + 256*j;
      int kb = flat >> 5, nb = (flat & 31) * 4;
      bv[j] = *reinterpret_cast<const f32x4*>(W + (size_t)(k0 + kb) * DN + n0 + nb);
    }
    __syncthreads();   // protect previous iteration's LDS reads
    #pragma unroll
    for (int i = 0; i < 4; ++i)
      #pragma unroll
      for (int c = 0; c < 4; ++c)
        As[aseg + i*4 + c][am] = av[i][c];
    #pragma unroll
    for (int j = 0; j < 4; ++j){
      int flat = t + 256*j;
      int kb = flat >> 5, nb = (flat & 31) * 4;
      *reinterpret_cast<f32x4*>(&Bs[kb][nb]) = bv[j];
    }
    __syncthreads();
    #pragma unroll
    for (int k = 0; k < 32; ++k){
      float a[8], b[8];
      *reinterpret_cast<f32x4*>(a)     = *reinterpret_cast<const f32x4*>(&As[k][ty*4]);
      *reinterpret_cast<f32x4*>(a + 4) = *reinterpret_cast<const f32x4*>(&As[k][64 + ty*4]);
      *reinterpret_cast<f32x4*>(b)     = *reinterpret_cast<const f32x4*>(&Bs[k][tx*4]);
      *reinterpret_cast<f32x4*>(b + 4) = *reinterpret_cast<const f32x4*>(&Bs[k][64 + tx*4]);
      #pragma unroll
      for (int i = 0; i < 8; ++i)
        #pragma unroll
        for (int jj = 0; jj < 8; ++jj)
          acc[i][jj] = fmaf(a[i], b[jj], acc[i][jj]);
    }
  }
  float bcol[8];
  #pragma unroll
  for (int j = 0; j < 4; ++j){ bcol[j] = bias[n0 + tx*4 + j]; bcol[4+j] = bias[n0 + 64 + tx*4 + j]; }
  #pragma unroll
  for (int i = 0; i < 8; ++i){
    const int row = m0 + (i < 4 ? ty*4 + i : 64 + ty*4 + (i - 4));
    float* dst = Y + (size_t)row * DN + n0;
    f32x4 v0, v1;
    #pragma unroll
    for (int j = 0; j < 4; ++j){ float v = acc[i][j] + bcol[j];     v0[j] = v > 0.f ? v : 0.f; }
    #pragma unroll
    for (int j = 0; j < 4; ++j){ float v = acc[i][4+j] + bcol[4+j]; v1[j] = v > 0.f ? v : 0.f; }
    *reinterpret_cast<f32x4*>(dst + tx*4)      = v0;
    *reinterpret_cast<f32x4*>(dst + 64 + tx*4) = v1;
  }
}

// ---------- router logits + softmax + argmax: eid[t], gate[t] = max prob ----------
__global__ __launch_bounds__(256) void k_router_logits(const float* __restrict__ R1, const float* __restrict__ W2,
                                                       const float* __restrict__ B2, int* __restrict__ eid,
                                                       float* __restrict__ gate){
  __shared__ float w2s[EN][DN];  // transposed [e][k]: bank = k%32 -> 2-way max
  __shared__ float b2s[EN];
  const int t = threadIdx.x;
  #pragma unroll
  for (int j = 0; j < 32; ++j){
    int flat = t + 256*j;
    w2s[flat & 7][flat >> 3] = W2[flat];
  }
  if (t < EN) b2s[t] = B2[t];
  __syncthreads();
  const int wid = t >> 6, lane = t & 63;
  const int token = blockIdx.x * 4 + wid;
  const float* row = R1 + (size_t)token * DN;
  float acc[8] = {};
  for (int i = 0; i < 16; ++i){
    int k = lane + 64*i;             // fully-coalesced scalar loads
    float v = row[k];
    #pragma unroll
    for (int e = 0; e < 8; ++e) acc[e] = fmaf(v, w2s[e][k], acc[e]);
  }
  #pragma unroll
  for (int e = 0; e < 8; ++e){
    float s = acc[e];
    #pragma unroll
    for (int off = 32; off > 0; off >>= 1) s += __shfl_xor(s, off);
    acc[e] = s + b2s[e];
  }
  float best = acc[0]; int be = 0;
  #pragma unroll
  for (int e = 1; e < 8; ++e) if (acc[e] > best){ best = acc[e]; be = e; }  // first-max, matches argmax
  float sum = 0.f;
  #pragma unroll
  for (int e = 0; e < 8; ++e) sum += __expf(acc[e] - best);
  if (lane == 0){ eid[token] = be; gate[token] = 1.0f / sum; }  // gate = probs[t, eid]
}

// ---------- dispatch: per-chunk histogram -> exclusive scan -> slot assignment ----------
__global__ __launch_bounds__(256) void k_count(const int* __restrict__ eid, int* __restrict__ counts){
  __shared__ int h[EN];
  const int t = threadIdx.x;
  if (t < EN) h[t] = 0;
  __syncthreads();
  atomicAdd(&h[eid[blockIdx.x * 256 + t]], 1);
  __syncthreads();
  if (t < EN) counts[blockIdx.x * EN + t] = h[t];
}

__global__ void k_scan(const int* __restrict__ counts, int* __restrict__ offs){
  const int e = threadIdx.x;
  if (e < EN){
    int run = 0;
    for (int c = 0; c < TN/256; ++c){
      offs[c * EN + e] = run;
      run += counts[c * EN + e];
    }
  }
}

__global__ __launch_bounds__(256) void k_assign(const int* __restrict__ eid, const int* __restrict__ offs,
                                                int* __restrict__ idx){
  __shared__ int wcnt[4][EN];
  const int t = threadIdx.x;
  const int w = t >> 6, lane = t & 63;
  const int token = blockIdx.x * 256 + t;
  const int e = eid[token];
  unsigned long long mymask = 0;
  #pragma unroll
  for (int ee = 0; ee < EN; ++ee){
    unsigned long long m = __ballot(e == ee);
    if (ee == e) mymask = m;
    if (lane == 0) wcnt[w][ee] = __popcll(m);
  }
  const int rank = __popcll(mymask & ((1ull << lane) - 1ull));
  __syncthreads();
  int pre = 0;
  for (int wi = 0; wi < w; ++wi) pre += wcnt[wi][e];
  const int pos = offs[blockIdx.x * EN + e] + pre + rank;  // exact cumsum-order rank
  if (pos < CAPN) idx[e * CAPN + pos] = token;             // else dropped
}

// ---------- gather x rows -> bf16 xe[slot][k] (zeros for empty slots) ----------
__global__ __launch_bounds__(256) void k_gather(const float* __restrict__ X, const int* __restrict__ idx,
                                                u16* __restrict__ xe){
  const int slot = blockIdx.x;
  const int tok = idx[slot];
  const int t = threadIdx.x;
  unsigned lo = 0, hi = 0;
  if (tok >= 0){
    f32x4 v = *reinterpret_cast<const f32x4*>(X + (size_t)tok * DN + t*4);
    lo = (unsigned)f2bf(v[0]) | ((unsigned)f2bf(v[1]) << 16);
    hi = (unsigned)f2bf(v[2]) | ((unsigned)f2bf(v[3]) << 16);
  }
  uint2 o; o.x = lo; o.y = hi;
  *reinterpret_cast<uint2*>(xe + (size_t)slot * DN + t*4) = o;
}

// ---------- expert GEMMs: m97 structure — global_load_lds, linear [128][32] LDS ----------
// A: bf16 [E*CAPN][K] row-major; Bt: bf16 [E][N][K] (pre-transposed weights)
// EPI 0: Hout = bf16 relu(A@B + b1)     EPI 1: Out[token] = (A@B + b2) * gate[token]
template<int EPI>
__global__ __launch_bounds__(256) void k_ffn(const u16* __restrict__ A, const u16* __restrict__ Bt,
                                             const float* __restrict__ bias, const int* __restrict__ idx,
                                             const float* __restrict__ gate, u16* __restrict__ Hout,
                                             float* __restrict__ Out, int K, int N){
  __shared__ u16 As[128 * 32];   // linear: row stride 64B (global_load_lds needs linear dest, m104)
  __shared__ u16 Bs[128 * 32];
  const int e = blockIdx.z;
  const int m0 = blockIdx.y * 128, n0 = blockIdx.x * 128;
  const u16* Ae = A + ((size_t)e * CAPN + m0) * K;
  const u16* Be = Bt + ((size_t)e * N + n0) * K;
  const int t = threadIdx.x;
  const int wid = t >> 6, lane = t & 63;
  const int wr = wid >> 1, wc = wid & 1;
  const int r16 = lane & 15, kseg = lane >> 4;
  f32x4 acc[4][4] = {};
  // staging map: thread t covers LDS bytes t*16 (row t/4, col-seg t%4); lane*16 auto-added by HW
  const u16* ga = Ae + (size_t)(t >> 2) * K + (t & 3) * 8;
  const u16* gb = Be + (size_t)(t >> 2) * K + (t & 3) * 8;
  char* AsB = (char*)As + wid * 1024;   // wave-uniform LDS base
  char* BsB = (char*)Bs + wid * 1024;
  for (int k0 = 0; k0 < K; k0 += 32){
    __syncthreads();                    // prior tile's ds_reads retired before overwrite
    GLOAD16(ga + k0,                AsB);
    GLOAD16(ga + (size_t)64*K + k0, AsB + 4096);
    GLOAD16(gb + k0,                BsB);
    GLOAD16(gb + (size_t)64*K + k0, BsB + 4096);
    __syncthreads();                    // compiler drains vmcnt(0) before s_barrier (m97 semantics)
    s16x8 af[4], bf[4];
    #pragma unroll
    for (int fr = 0; fr < 4; ++fr)
      af[fr] = *reinterpret_cast<const s16x8*>(&As[(wr*64 + fr*16 + r16) * 32 + kseg*8]);
    #pragma unroll
    for (int fc = 0; fc < 4; ++fc)
      bf[fc] = *reinterpret_cast<const s16x8*>(&Bs[(wc*64 + fc*16 + r16) * 32 + kseg*8]);
    #pragma unroll
    for (int fr = 0; fr < 4; ++fr)
      #pragma unroll
      for (int fc = 0; fc < 4; ++fc)
        acc[fr][fc] = __builtin_amdgcn_mfma_f32_16x16x32_bf16(af[fr], bf[fc], acc[fr][fc], 0, 0, 0);
  }
  // C/D layout: col = lane&15, row = (lane>>4)*4 + reg  [guide §3, m89-verified]
  if (EPI == 0){
    #pragma unroll
    for (int fc = 0; fc < 4; ++fc){
      const int col = n0 + wc*64 + fc*16 + r16;
      const float bc = bias[e * N + col];
      #pragma unroll
      for (int fr = 0; fr < 4; ++fr){
        #pragma unroll
        for (int r = 0; r < 4; ++r){
          const int row = m0 + wr*64 + fr*16 + kseg*4 + r;
          float v = acc[fr][fc][r] + bc;
          v = v > 0.f ? v : 0.f;
          Hout[((size_t)e * CAPN + row) * N + col] = f2bf(v);
        }
      }
    }
  } else {
    #pragma unroll
    for (int fr = 0; fr < 4; ++fr){
      #pragma unroll
      for (int r = 0; r < 4; ++r){
        const int row = m0 + wr*64 + fr*16 + kseg*4 + r;
        const int tok = idx[e * CAPN + row];
        if (tok < 0) continue;                    // empty slot
        const float g = gate[tok];
        #pragma unroll
        for (int fc = 0; fc < 4; ++fc){
          const int col = n0 + wc*64 + fc*16 + r16;
          Out[(size_t)tok * DN + col] = (acc[fr][fc][r] + bias[e * N + col]) * g;
        }
      }
    }
  }
}

extern "C" void kernel_launch(void* const* d_in, const int* in_sizes, int n_in,
                              void* d_out, int out_size, void* d_ws, size_t ws_size,
                              hipStream_t stream){
  const float* x   = (const float*)d_in[0];
  const float* wr1 = (const float*)d_in[1];
  const float* br1 = (const float*)d_in[2];
  const float* wr2 = (const float*)d_in[3];
  const float* br2 = (const float*)d_in[4];
  const float* w1  = (const float*)d_in[5];
  const float* b1  = (const float*)d_in[6];
  const float* w2  = (const float*)d_in[7];
  const float* b2  = (const float*)d_in[8];
  float* out = (float*)d_out;

  char* ws = (char*)d_ws;
  size_t off = 0;
  auto walloc = [&](size_t bytes) -> void* {
    void* p = ws + off;
    off += (bytes + 255) & ~(size_t)255;
    return p;
  };
  u16* hbuf   = (u16*)walloc((size_t)EN * CAPN * HN * 2);   // 128 MB; first 64 MB doubles as r1
  float* r1   = (float*)hbuf;                               // dead before ffn1 writes hbuf
  u16* xe     = (u16*)walloc((size_t)EN * CAPN * DN * 2);   // 32 MB
  u16* w1T    = (u16*)walloc((size_t)EN * HN * DN * 2);     // 64 MB
  u16* w2T    = (u16*)walloc((size_t)EN * HN * DN * 2);     // 64 MB
  int* eid    = (int*)walloc(TN * 4);
  float* gate = (float*)walloc(TN * 4);
  int* counts = (int*)walloc((TN/256) * EN * 4);
  int* offs   = (int*)walloc((TN/256) * EN * 4);
  int* idx    = (int*)walloc(EN * CAPN * 4);
  (void)in_sizes; (void)n_in; (void)out_size; (void)ws_size;

  k_transpose<<<dim3(HN/64, DN/64, EN), 256, 0, stream>>>(w1, w1T, DN, HN);  // (E,D,H)->(E,H,D)
  k_transpose<<<dim3(DN/64, HN/64, EN), 256, 0, stream>>>(w2, w2T, HN, DN);  // (E,H,D)->(E,D,H)
  k_router_gemm1<<<dim3(DN/128, TN/128), 256, 0, stream>>>(x, wr1, br1, r1);
  k_router_logits<<<dim3(TN/4), 256, 0, stream>>>(r1, wr2, br2, eid, gate);
  k_count<<<dim3(TN/256), 256, 0, stream>>>(eid, counts);
  k_scan<<<dim3(1), 64, 0, stream>>>(counts, offs);
  hipMemsetAsync(idx, 0xFF, (size_t)EN * CAPN * 4, stream);                  // -1 = empty slot
  k_assign<<<dim3(TN/256), 256, 0, stream>>>(eid, offs, idx);
  k_gather<<<dim3(EN * CAPN), 256, 0, stream>>>(x, idx, xe);
  k_ffn<0><<<dim3(HN/128, CAPN/128, EN), 256, 0, stream>>>(xe, w1T, b1, nullptr, nullptr, hbuf, nullptr, DN, HN);
  hipMemsetAsync(d_out, 0, (size_t)TN * DN * 4, stream);
  k_ffn<1><<<dim3(DN/128, CAPN/128, EN), 256, 0, stream>>>(hbuf, w2T, b2, idx, gate, nullptr, out, HN, DN);
}

// Round 4
// 1047.798 us; speedup vs baseline: 1.2696x; 1.1616x over previous
//
#include <hip/hip_runtime.h>

typedef short s16x8 __attribute__((ext_vector_type(8)));   // 8 bf16 MFMA frag (per guide §3)
typedef float f32x4 __attribute__((ext_vector_type(4)));
typedef unsigned short u16;
typedef u16 u16x8 __attribute__((ext_vector_type(8)));
typedef u16 u16x4 __attribute__((ext_vector_type(4)));

constexpr int TN = 16384;
constexpr int DN = 1024;
constexpr int EN = 8;
constexpr int HN = 4096;
constexpr int CAPN = 2048;  // CAP_FACTOR * T / E

// async global->LDS, 16B per lane; lds ptr must be wave-uniform (lane*16 auto-added)
#define GLOAD16(g, l) __builtin_amdgcn_global_load_lds( \
    (const __attribute__((address_space(1))) unsigned int*)(g), \
    (__attribute__((address_space(3))) unsigned int*)(l), 16, 0, 0)

__device__ __forceinline__ u16 f2bf(float x){  // round-to-nearest-even f32 -> bf16
  unsigned u = __float_as_uint(x);
  u = (u + 0x7fffu + ((u >> 16) & 1u)) >> 16;
  return (u16)u;
}

// 3-term bf16 split: x = hi + lo + lo2 + delta, |delta| <= 2^-27 |x|
__device__ __forceinline__ void split3(float x, u16& h, u16& l, u16& l2){
  h = f2bf(x);
  float r = x - __uint_as_float((unsigned)h << 16);
  l = f2bf(r);
  l2 = f2bf(r - __uint_as_float((unsigned)l << 16));
}

// ---------- fp32 (E,R,C) -> bf16 (E,C,R)  (FFN weights pre-transpose+convert) ----------
__global__ __launch_bounds__(256) void k_transpose(const float* __restrict__ in, u16* __restrict__ out,
                                                   int R, int C){
  __shared__ float tile[64][65];  // +1 pad: column reads conflict-free
  const int e = blockIdx.z;
  const int r0 = blockIdx.y * 64, c0 = blockIdx.x * 64;
  const float* ine = in + (size_t)e * R * C;
  u16* oute = out + (size_t)e * R * C;
  const int t = threadIdx.x;
  {
    const int dr = t >> 2, cs = (t & 3) * 16;
    const float* src = ine + (size_t)(r0 + dr) * C + (c0 + cs);
    #pragma unroll
    for (int i = 0; i < 4; ++i){
      f32x4 v = *reinterpret_cast<const f32x4*>(src + i * 4);
      #pragma unroll
      for (int c = 0; c < 4; ++c) tile[dr][cs + i*4 + c] = v[c];
    }
  }
  __syncthreads();
  {
    const int dn = t >> 2, ks = (t & 3) * 16;
    u16x8 lo, hi;
    #pragma unroll
    for (int i = 0; i < 8; ++i) lo[i] = f2bf(tile[ks + i][dn]);
    #pragma unroll
    for (int i = 0; i < 8; ++i) hi[i] = f2bf(tile[ks + 8 + i][dn]);
    u16* dst = oute + (size_t)(c0 + dn) * R + (r0 + ks);
    *reinterpret_cast<u16x8*>(dst) = lo;
    *reinterpret_cast<u16x8*>(dst + 8) = hi;
  }
}

// ---------- x -> 3 bf16 planes (elementwise) ----------
__global__ __launch_bounds__(256) void k_split_x(const float* __restrict__ X, u16* __restrict__ H,
                                                 u16* __restrict__ L, u16* __restrict__ L2){
  const size_t i = ((size_t)blockIdx.x * 256 + threadIdx.x) * 4;
  f32x4 v = *reinterpret_cast<const f32x4*>(X + i);
  u16x4 h, l, l2;
  #pragma unroll
  for (int j = 0; j < 4; ++j){ u16 a, b, c; split3(v[j], a, b, c); h[j] = a; l[j] = b; l2[j] = c; }
  *reinterpret_cast<u16x4*>(H + i)  = h;
  *reinterpret_cast<u16x4*>(L + i)  = l;
  *reinterpret_cast<u16x4*>(L2 + i) = l2;
}

// ---------- wr1 [K][N] -> wr1^T 3 bf16 planes [N][K] ----------
__global__ __launch_bounds__(256) void k_split_wT(const float* __restrict__ in, u16* __restrict__ oh,
                                                  u16* __restrict__ ol, u16* __restrict__ ol2){
  __shared__ float tile[64][65];
  const int r0 = blockIdx.y * 64, c0 = blockIdx.x * 64;   // in [1024][1024]
  const int t = threadIdx.x;
  {
    const int dr = t >> 2, cs = (t & 3) * 16;
    const float* src = in + (size_t)(r0 + dr) * DN + (c0 + cs);
    #pragma unroll
    for (int i = 0; i < 4; ++i){
      f32x4 v = *reinterpret_cast<const f32x4*>(src + i * 4);
      #pragma unroll
      for (int c = 0; c < 4; ++c) tile[dr][cs + i*4 + c] = v[c];
    }
  }
  __syncthreads();
  {
    const int dn = t >> 2, ks = (t & 3) * 16;
    u16x8 h0, h1, l0, l1, m0v, m1v;
    #pragma unroll
    for (int i = 0; i < 8; ++i){ u16 a,b,c; split3(tile[ks + i][dn], a,b,c);     h0[i]=a; l0[i]=b; m0v[i]=c; }
    #pragma unroll
    for (int i = 0; i < 8; ++i){ u16 a,b,c; split3(tile[ks + 8 + i][dn], a,b,c); h1[i]=a; l1[i]=b; m1v[i]=c; }
    const size_t o = (size_t)(c0 + dn) * DN + (r0 + ks);
    *reinterpret_cast<u16x8*>(oh + o) = h0;  *reinterpret_cast<u16x8*>(oh + o + 8) = h1;
    *reinterpret_cast<u16x8*>(ol + o) = l0;  *reinterpret_cast<u16x8*>(ol + o + 8) = l1;
    *reinterpret_cast<u16x8*>(ol2 + o) = m0v; *reinterpret_cast<u16x8*>(ol2 + o + 8) = m1v;
  }
}

// ---------- router GEMM1 on MFMA: r1 = relu(x @ wr1 + br1) via 3-term split, 6 products ----------
// error: dropped terms <= ~3e-8*|x||w| per elem -> logit err ~1e-6 (fp32-reordering class, no argmax flips)
__global__ __launch_bounds__(256) void k_router_mfma(
    const u16* __restrict__ Ah, const u16* __restrict__ Al, const u16* __restrict__ Al2,
    const u16* __restrict__ Bh, const u16* __restrict__ Bl, const u16* __restrict__ Bl2,
    const float* __restrict__ bias, float* __restrict__ Y){
  constexpr int K = DN;
  __shared__ u16 As[3 * 128 * 32];   // plane-major, linear [128][32] each (m97/m104)
  __shared__ u16 Bs[3 * 128 * 32];
  const int m0 = blockIdx.y * 128, n0 = blockIdx.x * 128;
  const int t = threadIdx.x;
  const int wid = t >> 6, lane = t & 63;
  const int wr = wid >> 1, wc = wid & 1;
  const int r16 = lane & 15, kseg = lane >> 4;
  f32x4 acc[4][4] = {};
  const size_t aoff = (size_t)(m0 + (t >> 2)) * K + (t & 3) * 8;
  const size_t boff = (size_t)(n0 + (t >> 2)) * K + (t & 3) * 8;
  const u16* gah = Ah + aoff;  const u16* gal = Al + aoff;  const u16* gam = Al2 + aoff;
  const u16* gbh = Bh + boff;  const u16* gbl = Bl + boff;  const u16* gbm = Bl2 + boff;
  char* A0 = (char*)As + wid * 1024;  char* A1 = A0 + 8192;  char* A2 = A1 + 8192;
  char* B0 = (char*)Bs + wid * 1024;  char* B1 = B0 + 8192;  char* B2 = B1 + 8192;
  constexpr size_t R64 = (size_t)64 * K;
  for (int k0 = 0; k0 < K; k0 += 32){
    __syncthreads();
    GLOAD16(gah + k0, A0); GLOAD16(gah + R64 + k0, A0 + 4096);
    GLOAD16(gal + k0, A1); GLOAD16(gal + R64 + k0, A1 + 4096);
    GLOAD16(gam + k0, A2); GLOAD16(gam + R64 + k0, A2 + 4096);
    GLOAD16(gbh + k0, B0); GLOAD16(gbh + R64 + k0, B0 + 4096);
    GLOAD16(gbl + k0, B1); GLOAD16(gbl + R64 + k0, B1 + 4096);
    GLOAD16(gbm + k0, B2); GLOAD16(gbm + R64 + k0, B2 + 4096);
    __syncthreads();
    s16x8 ah[4], al[4], am[4], bh[4], bl[4], bm[4];
    #pragma unroll
    for (int fr = 0; fr < 4; ++fr){
      const int ro = (wr*64 + fr*16 + r16) * 32 + kseg*8;
      ah[fr] = *reinterpret_cast<const s16x8*>(&As[ro]);
      al[fr] = *reinterpret_cast<const s16x8*>(&As[128*32 + ro]);
      am[fr] = *reinterpret_cast<const s16x8*>(&As[2*128*32 + ro]);
    }
    #pragma unroll
    for (int fc = 0; fc < 4; ++fc){
      const int ro = (wc*64 + fc*16 + r16) * 32 + kseg*8;
      bh[fc] = *reinterpret_cast<const s16x8*>(&Bs[ro]);
      bl[fc] = *reinterpret_cast<const s16x8*>(&Bs[128*32 + ro]);
      bm[fc] = *reinterpret_cast<const s16x8*>(&Bs[2*128*32 + ro]);
    }
    #pragma unroll
    for (int fr = 0; fr < 4; ++fr)
      #pragma unroll
      for (int fc = 0; fc < 4; ++fc){
        f32x4 c = acc[fr][fc];
        c = __builtin_amdgcn_mfma_f32_16x16x32_bf16(ah[fr], bh[fc], c, 0, 0, 0);
        c = __builtin_amdgcn_mfma_f32_16x16x32_bf16(ah[fr], bl[fc], c, 0, 0, 0);
        c = __builtin_amdgcn_mfma_f32_16x16x32_bf16(al[fr], bh[fc], c, 0, 0, 0);
        c = __builtin_amdgcn_mfma_f32_16x16x32_bf16(al[fr], bl[fc], c, 0, 0, 0);
        c = __builtin_amdgcn_mfma_f32_16x16x32_bf16(ah[fr], bm[fc], c, 0, 0, 0);
        c = __builtin_amdgcn_mfma_f32_16x16x32_bf16(am[fr], bh[fc], c, 0, 0, 0);
        acc[fr][fc] = c;
      }
  }
  // C/D layout: col = lane&15, row = (lane>>4)*4 + reg
  #pragma unroll
  for (int fc = 0; fc < 4; ++fc){
    const int col = n0 + wc*64 + fc*16 + r16;
    const float bc = bias[col];
    #pragma unroll
    for (int fr = 0; fr < 4; ++fr){
      #pragma unroll
      for (int r = 0; r < 4; ++r){
        const int row = m0 + wr*64 + fr*16 + kseg*4 + r;
        float v = acc[fr][fc][r] + bc;
        Y[(size_t)row * DN + col] = v > 0.f ? v : 0.f;
      }
    }
  }
}

// ---------- router logits + softmax + argmax: eid[t], gate[t] = max prob ----------
__global__ __launch_bounds__(256) void k_router_logits(const float* __restrict__ R1, const float* __restrict__ W2,
                                                       const float* __restrict__ B2, int* __restrict__ eid,
                                                       float* __restrict__ gate){
  __shared__ float w2s[EN][DN];  // transposed [e][k]
  __shared__ float b2s[EN];
  const int t = threadIdx.x;
  #pragma unroll
  for (int j = 0; j < 32; ++j){
    int flat = t + 256*j;
    w2s[flat & 7][flat >> 3] = W2[flat];
  }
  if (t < EN) b2s[t] = B2[t];
  __syncthreads();
  const int wid = t >> 6, lane = t & 63;
  const int token = blockIdx.x * 4 + wid;
  const float* row = R1 + (size_t)token * DN;
  float acc[8] = {};
  for (int i = 0; i < 16; ++i){
    int k = lane + 64*i;
    float v = row[k];
    #pragma unroll
    for (int e = 0; e < 8; ++e) acc[e] = fmaf(v, w2s[e][k], acc[e]);
  }
  #pragma unroll
  for (int e = 0; e < 8; ++e){
    float s = acc[e];
    #pragma unroll
    for (int off = 32; off > 0; off >>= 1) s += __shfl_xor(s, off);
    acc[e] = s + b2s[e];
  }
  float best = acc[0]; int be = 0;
  #pragma unroll
  for (int e = 1; e < 8; ++e) if (acc[e] > best){ best = acc[e]; be = e; }  // first-max = argmax
  float sum = 0.f;
  #pragma unroll
  for (int e = 0; e < 8; ++e) sum += __expf(acc[e] - best);
  if (lane == 0){ eid[token] = be; gate[token] = 1.0f / sum; }  // gate = probs[t, eid]
}

// ---------- dispatch: per-chunk histogram -> exclusive scan -> slot assignment ----------
__global__ __launch_bounds__(256) void k_count(const int* __restrict__ eid, int* __restrict__ counts){
  __shared__ int h[EN];
  const int t = threadIdx.x;
  if (t < EN) h[t] = 0;
  __syncthreads();
  atomicAdd(&h[eid[blockIdx.x * 256 + t]], 1);
  __syncthreads();
  if (t < EN) counts[blockIdx.x * EN + t] = h[t];
}

__global__ void k_scan(const int* __restrict__ counts, int* __restrict__ offs){
  const int e = threadIdx.x;
  if (e < EN){
    int run = 0;
    for (int c = 0; c < TN/256; ++c){
      offs[c * EN + e] = run;
      run += counts[c * EN + e];
    }
  }
}

__global__ __launch_bounds__(256) void k_assign(const int* __restrict__ eid, const int* __restrict__ offs,
                                                int* __restrict__ idx){
  __shared__ int wcnt[4][EN];
  const int t = threadIdx.x;
  const int w = t >> 6, lane = t & 63;
  const int token = blockIdx.x * 256 + t;
  const int e = eid[token];
  unsigned long long mymask = 0;
  #pragma unroll
  for (int ee = 0; ee < EN; ++ee){
    unsigned long long m = __ballot(e == ee);
    if (ee == e) mymask = m;
    if (lane == 0) wcnt[w][ee] = __popcll(m);
  }
  const int rank = __popcll(mymask & ((1ull << lane) - 1ull));
  __syncthreads();
  int pre = 0;
  for (int wi = 0; wi < w; ++wi) pre += wcnt[wi][e];
  const int pos = offs[blockIdx.x * EN + e] + pre + rank;  // exact cumsum-order rank
  if (pos < CAPN) idx[e * CAPN + pos] = token;             // else dropped
}

// ---------- expert GEMMs: m97 structure — global_load_lds, linear [128][32] LDS ----------
// EPI 0: A = xhi token rows, INDIRECT staging via idx (per-lane global src, m104); Hout = bf16 relu(A@B + b1)
// EPI 1: A = hbuf dense slot rows;  Out[token] = (A@B + b2) * gate[token]
template<int EPI>
__global__ __launch_bounds__(256) void k_ffn(const u16* __restrict__ A, const u16* __restrict__ Bt,
                                             const float* __restrict__ bias, const int* __restrict__ idx,
                                             const float* __restrict__ gate, const u16* __restrict__ zrow,
                                             u16* __restrict__ Hout, float* __restrict__ Out, int K, int N){
  __shared__ u16 As[128 * 32];
  __shared__ u16 Bs[128 * 32];
  const int e = blockIdx.z;
  const int m0 = blockIdx.y * 128, n0 = blockIdx.x * 128;
  const u16* Be = Bt + ((size_t)e * N + n0) * K;
  const int t = threadIdx.x;
  const int wid = t >> 6, lane = t & 63;
  const int wr = wid >> 1, wc = wid & 1;
  const int r16 = lane & 15, kseg = lane >> 4;
  f32x4 acc[4][4] = {};
  const u16 *ga0, *ga1;
  if (EPI == 0){
    const int s0 = e * CAPN + m0 + (t >> 2);
    const int tok0 = idx[s0], tok1 = idx[s0 + 64];
    ga0 = (tok0 < 0 ? zrow : A + (size_t)tok0 * K) + (t & 3) * 8;
    ga1 = (tok1 < 0 ? zrow : A + (size_t)tok1 * K) + (t & 3) * 8;
  } else {
    const u16* Ae = A + ((size_t)e * CAPN + m0) * K;
    ga0 = Ae + (size_t)(t >> 2) * K + (t & 3) * 8;
    ga1 = ga0 + (size_t)64 * K;
  }
  const u16* gb = Be + (size_t)(t >> 2) * K + (t & 3) * 8;
  char* AsB = (char*)As + wid * 1024;   // wave-uniform LDS base
  char* BsB = (char*)Bs + wid * 1024;
  for (int k0 = 0; k0 < K; k0 += 32){
    __syncthreads();                    // prior tile's ds_reads retired before overwrite
    GLOAD16(ga0 + k0, AsB);
    GLOAD16(ga1 + k0, AsB + 4096);
    GLOAD16(gb + k0,                BsB);
    GLOAD16(gb + (size_t)64*K + k0, BsB + 4096);
    __syncthreads();
    s16x8 af[4], bf[4];
    #pragma unroll
    for (int fr = 0; fr < 4; ++fr)
      af[fr] = *reinterpret_cast<const s16x8*>(&As[(wr*64 + fr*16 + r16) * 32 + kseg*8]);
    #pragma unroll
    for (int fc = 0; fc < 4; ++fc)
      bf[fc] = *reinterpret_cast<const s16x8*>(&Bs[(wc*64 + fc*16 + r16) * 32 + kseg*8]);
    #pragma unroll
    for (int fr = 0; fr < 4; ++fr)
      #pragma unroll
      for (int fc = 0; fc < 4; ++fc)
        acc[fr][fc] = __builtin_amdgcn_mfma_f32_16x16x32_bf16(af[fr], bf[fc], acc[fr][fc], 0, 0, 0);
  }
  // C/D layout: col = lane&15, row = (lane>>4)*4 + reg
  if (EPI == 0){
    #pragma unroll
    for (int fc = 0; fc < 4; ++fc){
      const int col = n0 + wc*64 + fc*16 + r16;
      const float bc = bias[e * N + col];
      #pragma unroll
      for (int fr = 0; fr < 4; ++fr){
        #pragma unroll
        for (int r = 0; r < 4; ++r){
          const int row = m0 + wr*64 + fr*16 + kseg*4 + r;
          float v = acc[fr][fc][r] + bc;
          v = v > 0.f ? v : 0.f;
          Hout[((size_t)e * CAPN + row) * N + col] = f2bf(v);
        }
      }
    }
  } else {
    #pragma unroll
    for (int fr = 0; fr < 4; ++fr){
      #pragma unroll
      for (int r = 0; r < 4; ++r){
        const int row = m0 + wr*64 + fr*16 + kseg*4 + r;
        const int tok = idx[e * CAPN + row];
        if (tok < 0) continue;                    // empty slot
        const float g = gate[tok];
        #pragma unroll
        for (int fc = 0; fc < 4; ++fc){
          const int col = n0 + wc*64 + fc*16 + r16;
          Out[(size_t)tok * DN + col] = (acc[fr][fc][r] + bias[e * N + col]) * g;
        }
      }
    }
  }
}

extern "C" void kernel_launch(void* const* d_in, const int* in_sizes, int n_in,
                              void* d_out, int out_size, void* d_ws, size_t ws_size,
                              hipStream_t stream){
  const float* x   = (const float*)d_in[0];
  const float* wr1 = (const float*)d_in[1];
  const float* br1 = (const float*)d_in[2];
  const float* wr2 = (const float*)d_in[3];
  const float* br2 = (const float*)d_in[4];
  const float* w1  = (const float*)d_in[5];
  const float* b1  = (const float*)d_in[6];
  const float* w2  = (const float*)d_in[7];
  const float* b2  = (const float*)d_in[8];
  float* out = (float*)d_out;

  char* ws = (char*)d_ws;
  size_t off = 0;
  auto walloc = [&](size_t bytes) -> void* {
    void* p = ws + off;
    off += (bytes + 255) & ~(size_t)255;
    return p;
  };
  u16* hbuf   = (u16*)walloc((size_t)EN * CAPN * HN * 2);   // 128 MiB
  float* r1   = (float*)hbuf;                               // [0,64M): fp32 r1, dead before ffn0
  u16* xlo    = (u16*)((char*)hbuf + ((size_t)64 << 20));   // [64M,96M): dead before ffn0
  u16* xlo2   = (u16*)((char*)hbuf + ((size_t)96 << 20));   // [96M,128M): dead before ffn0
  u16* xhi    = (u16*)walloc((size_t)TN * DN * 2);          // 32 MiB (also FFN0 A-matrix)
  u16* w1T    = (u16*)walloc((size_t)EN * HN * DN * 2);     // 64 MiB
  u16* w2T    = (u16*)walloc((size_t)EN * HN * DN * 2);     // 64 MiB
  u16* wTh    = (u16*)walloc((size_t)DN * DN * 2);          // 2 MiB x3
  u16* wTl    = (u16*)walloc((size_t)DN * DN * 2);
  u16* wTl2   = (u16*)walloc((size_t)DN * DN * 2);
  int* eid    = (int*)walloc(TN * 4);
  float* gate = (float*)walloc(TN * 4);
  int* counts = (int*)walloc((TN/256) * EN * 4);
  int* offs   = (int*)walloc((TN/256) * EN * 4);
  int* idx    = (int*)walloc(EN * CAPN * 4);
  u16* zrow   = (u16*)walloc(DN * 2);                       // zero row for empty slots
  (void)in_sizes; (void)n_in; (void)out_size; (void)ws_size;

  k_transpose<<<dim3(HN/64, DN/64, EN), 256, 0, stream>>>(w1, w1T, DN, HN);  // (E,D,H)->(E,H,D)
  k_transpose<<<dim3(DN/64, HN/64, EN), 256, 0, stream>>>(w2, w2T, HN, DN);  // (E,H,D)->(E,D,H)
  k_split_x<<<dim3((TN*DN)/1024), 256, 0, stream>>>(x, xhi, xlo, xlo2);
  k_split_wT<<<dim3(DN/64, DN/64), 256, 0, stream>>>(wr1, wTh, wTl, wTl2);
  k_router_mfma<<<dim3(DN/128, TN/128), 256, 0, stream>>>(xhi, xlo, xlo2, wTh, wTl, wTl2, br1, r1);
  k_router_logits<<<dim3(TN/4), 256, 0, stream>>>(r1, wr2, br2, eid, gate);
  k_count<<<dim3(TN/256), 256, 0, stream>>>(eid, counts);
  k_scan<<<dim3(1), 64, 0, stream>>>(counts, offs);
  hipMemsetAsync(idx, 0xFF, (size_t)EN * CAPN * 4, stream);                  // -1 = empty slot
  k_assign<<<dim3(TN/256), 256, 0, stream>>>(eid, offs, idx);
  hipMemsetAsync(zrow, 0, DN * 2, stream);
  k_ffn<0><<<dim3(HN/128, CAPN/128, EN), 256, 0, stream>>>(xhi, w1T, b1, idx, nullptr, zrow, hbuf, nullptr, DN, HN);
  hipMemsetAsync(d_out, 0, (size_t)TN * DN * 4, stream);
  k_ffn<1><<<dim3(DN/128, CAPN/128, EN), 256, 0, stream>>>(hbuf, w2T, b2, idx, gate, nullptr, nullptr, out, HN, DN);
}